// Round 9
// baseline (595.159 us; speedup 1.0000x reference)
//
#include <hip/hip_runtime.h>
#include <math.h>

// Max-plus DP: out[b,t,k] = x[b,t,k] + max(out[b,t-1,k], out[b,t-1,k-1])
// 32 batches x 8 column groups = 256 blocks, 1 wave each, 2 cols/lane.
//
// Round-9 theory: rounds 5-8 eliminated drains, DS-queue pollution, and
// schedule pinning; T_tile stayed ~8.3Kcy. The one op never removed from
// the recurrence: per-row __shfl_up — DS-class, ~120cy latency, consumed
// one row later, with only ~10cy of VALU to hide it and 1 wave/CU (no
// TLP). 32 rows x ~120cy ~= the whole tile time. Fix: replace the DS
// shift with DPP (VALU-class, ~2cy, no lgkmcnt):
//   left(lane i) = n1(lane i-1) via v_mov_b32_dpp row_shr:1 (ctrl 0x111);
//   lanes 16/32/48 patched with readlane(n1, 15/31/47) + selects (VALU).
// The row loop now issues ZERO DS ops. Everything else is byte-identical
// to the passing round-8 kernel: LDS staging via global_load_lds, batched
// tile-top ds_reads, register-packed boundary prefix publish, counted
// vmcnt(32)/vmcnt(48) (never 0 in the loop), lag flag protocol.

#define BB 32
#define TT 2048
#define KK 1024
#define GG 8
#define WW (KK / GG)      // 128 cols per group
#define RR 32             // rows per tile (flag granularity)
#define NT (TT / RR)      // 64 tiles

typedef __attribute__((address_space(1))) void GV;  // global
typedef __attribute__((address_space(3))) void LV;  // LDS

__global__ __launch_bounds__(64, 1)
void harddtw_dpp(const float* __restrict__ x, float* __restrict__ out,
                 int* __restrict__ flags, float* __restrict__ bws)
{
    const int bid  = blockIdx.x;
    const int g    = bid >> 5;   // column group 0..7
    const int b    = bid & 31;   // batch
    const int lane = threadIdx.x;
    const bool lz  = (lane == 0);
    const bool l16 = (lane == 16), l32 = (lane == 32), l48 = (lane == 48);

    const int k0 = g * WW;
    const int kc = k0 + (lane << 1);
    const size_t base = (size_t)b * TT * KK;

    float* ol = out + base + kc;               // out cursor (row 0)

    int* myflag = flags + bid;
    int* upflag = flags + bid - 32;            // same batch, group g-1
    float*       mybw = bws + ((size_t)(b * GG + g)) * TT;       // we publish
    const float* upbw = bws + ((size_t)(b * GG + g - 1)) * TT;   // we consume

    __shared__ float lds[2][RR * WW];          // 2 x 16KB x-tile buffers

    // Staging: inst i stages rows 2i,2i+1 (1KB linear LDS). Lane l covers
    // row 2i+(l>>5), float cols [4*(l&31), +4).
    const float* xstage = x + base + k0 + (size_t)(lane >> 5) * KK
                          + ((lane & 31) << 2);

    // Stage tile 0 into buffer 0 (latency overlaps the init flag wait).
    {
        const float* gp = xstage;
#pragma unroll
        for (int i = 0; i < RR / 2; ++i) {
            __builtin_amdgcn_global_load_lds((GV*)(void*)gp,
                                             (LV*)(void*)&lds[0][i * 256],
                                             16, 0, 0);
            gp += 2 * KK;
        }
    }

    float pv0 = 0.0f, pv1 = 0.0f;              // prev-row values (0 => row0 = x)
    float sh_prev = 0.0f;                      // left-neighbor pv1 from "row -1"
    float bcur = -INFINITY, bnxt = -INFINITY;  // boundary, lane j = row j-1 of tile
    unsigned long long bp[16];                 // lane63: packed boundary pairs
#pragma unroll
    for (int i = 0; i < 16; ++i) bp[i] = 0ull;

    if (g > 0) {
        // Boundary for tile 0 needs producer flag >= 1.
        while (__hip_atomic_load(upflag, __ATOMIC_RELAXED,
                                 __HIP_MEMORY_SCOPE_AGENT) < 1)
            __builtin_amdgcn_s_sleep(1);
        __asm__ volatile("" ::: "memory");
        if (lane == 0) {
            bcur = 0.0f;                       // row -1 virtual: max(0,0)
        } else if (lane < RR) {
            bcur = __hip_atomic_load(upbw + lane - 1, __ATOMIC_RELAXED,
                                     __HIP_MEMORY_SCOPE_AGENT);
        }
    }

    __asm__ volatile("s_waitcnt vmcnt(0)" ::: "memory");  // tile 0 staged
    int fpre = 0;                              // prefetched upflag value
    int buf = 0;

#pragma unroll 1
    for (int r = 0; r < NT; ++r) {
        const bool pub = (g < GG - 1);

        // [C] staging(r) ready: exact newer-op count 33-35 -> vmcnt(32).
        __asm__ volatile("s_waitcnt vmcnt(32)" ::: "memory");

        // [A] prefix: publish tile r-1's boundary values (packed last tile).
        if (pub && r > 0 && lane == 63) {
            unsigned long long* bwp =
                (unsigned long long*)(mybw + (size_t)(r - 1) * RR);
#pragma unroll
            for (int i = 0; i < 16; ++i)
                __hip_atomic_store(bwp + i, bp[i], __ATOMIC_RELAXED,
                                   __HIP_MEMORY_SCOPE_AGENT);
        }
        __asm__ volatile("" ::: "memory");     // pin A before B

        // [B] stage tile r+1 into the other buffer.
        if (r < NT - 1) {
            const float* gp = xstage + (size_t)(r + 1) * RR * KK;
            float* lp = &lds[buf ^ 1][0];
#pragma unroll
            for (int i = 0; i < RR / 2; ++i) {
                __builtin_amdgcn_global_load_lds((GV*)(void*)gp,
                                                 (LV*)(void*)(lp + i * 256),
                                                 16, 0, 0);
                gp += 2 * KK;
            }
        }
        __asm__ volatile("" ::: "memory");     // pin B before spin/rows

        // Flag check for next tile's boundary (prefetched fpre; spin only
        // as fallback).
        if (g > 0 && r < NT - 1) {
            if (fpre < r + 2) {
                while (__hip_atomic_load(upflag, __ATOMIC_RELAXED,
                                         __HIP_MEMORY_SCOPE_AGENT) < r + 2)
                    __builtin_amdgcn_s_sleep(1);
            }
            __asm__ volatile("" ::: "memory");
        }

        // Tile-wide batch read: all 32 rows into registers; the row loop
        // below issues NO DS ops at all.
        float2 td[RR];
#pragma unroll
        for (int j = 0; j < RR; ++j)
            td[j] = *(const float2*)&lds[buf][j * WW + (lane << 1)];
        __builtin_amdgcn_sched_barrier(0);

        float bpe = 0.0f;                      // even-row boundary stash
#pragma unroll
        for (int j = 0; j < RR; ++j) {
            float2 xv = td[j];
            float n1 = xv.y + fmaxf(pv1, pv0);
            // Boundary broadcast: uniform readlane (no DS).
            float bv = __int_as_float(
                __builtin_amdgcn_readlane(__float_as_int(bcur), j));
            float left = lz ? bv : sh_prev;    // built last row, pure VALU
            float n0 = xv.x + fmaxf(pv0, left);

            // Build next row's left in VALU: DPP row_shr:1 (ctrl 0x111)
            // shifts within 16-lane rows; lanes 16/32/48 patched via
            // readlane of lanes 15/31/47.
            int n1i = __float_as_int(n1);
            int di = __builtin_amdgcn_update_dpp(n1i, n1i, 0x111, 0xf, 0xf,
                                                 false);
            float sh = __int_as_float(di);
            float v15 = __int_as_float(__builtin_amdgcn_readlane(n1i, 15));
            float v31 = __int_as_float(__builtin_amdgcn_readlane(n1i, 31));
            float v47 = __int_as_float(__builtin_amdgcn_readlane(n1i, 47));
            if (l16) sh = v15;
            if (l32) sh = v31;
            if (l48) sh = v47;

            float2 o; o.x = n0; o.y = n1;
            *(float2*)ol = o;                  // plain store; gates nothing
            ol += KK;

            if ((j & 1) == 0) {
                bpe = n1;
            } else {
                union { float f[2]; unsigned long long u; } cv;
                cv.f[0] = bpe; cv.f[1] = n1;
                bp[j >> 1] = cv.u;             // pack for next tile's [A]
            }

            pv0 = n0; pv1 = n1; sh_prev = sh;
        }
        __asm__ volatile("" ::: "memory");     // pin rows before BN/FP/W

        // [BN] boundary rows for tile r+1 (late issue: auto-wait at next
        // tile's first readlane is encodable, never a drain).
        if (g > 0 && r < NT - 1) {
            if (lane < RR)
                bnxt = __hip_atomic_load(
                    upbw + (size_t)(r + 1) * RR + lane - 1,
                    __ATOMIC_RELAXED, __HIP_MEMORY_SCOPE_AGENT);
            // [FP] prefetch flag value for next tile's check.
            if (r < NT - 2)
                fpre = __hip_atomic_load(upflag, __ATOMIC_RELAXED,
                                         __HIP_MEMORY_SCOPE_AGENT);
        }
        bcur = bnxt;
        __asm__ volatile("" ::: "memory");

        // [W] publish flag = r (tiles 0..r-1 readable). Needs only the [A]
        // prefix stores done: exact newer-op count 50 -> vmcnt(48).
        if (pub && r > 0) {
            __asm__ volatile("s_waitcnt vmcnt(48)" ::: "memory");
            if (lz)
                __hip_atomic_store(myflag, r, __ATOMIC_RELAXED,
                                   __HIP_MEMORY_SCOPE_AGENT);
        }

        buf ^= 1;
    }

    // Post-loop: publish the final tile's boundary + terminal flag = NT.
    if (g < GG - 1) {
        if (lane == 63) {
            unsigned long long* bwp =
                (unsigned long long*)(mybw + (size_t)(NT - 1) * RR);
#pragma unroll
            for (int i = 0; i < 16; ++i)
                __hip_atomic_store(bwp + i, bp[i], __ATOMIC_RELAXED,
                                   __HIP_MEMORY_SCOPE_AGENT);
        }
        __asm__ volatile("s_waitcnt vmcnt(0)" ::: "memory");
        if (lz)
            __hip_atomic_store(myflag, NT, __ATOMIC_RELAXED,
                               __HIP_MEMORY_SCOPE_AGENT);
    }
}

extern "C" void kernel_launch(void* const* d_in, const int* in_sizes, int n_in,
                              void* d_out, int out_size, void* d_ws, size_t ws_size,
                              hipStream_t stream) {
    (void)in_sizes; (void)n_in; (void)out_size; (void)ws_size;
    const float* x = (const float*)d_in[0];
    float* out = (float*)d_out;
    int* flags = (int*)d_ws;
    float* bws = (float*)((char*)d_ws + 4096);  // [BB][GG][TT] floats = 2MB

    // ws is re-poisoned to 0xAA before every timed launch; flags must be 0.
    // bws needs no init: every read is flag-gated behind its producer.
    hipMemsetAsync(flags, 0, BB * GG * sizeof(int), stream);

    harddtw_dpp<<<dim3(BB * GG), dim3(64), 0, stream>>>(x, out, flags, bws);
}